// Round 17
// baseline (2404.466 us; speedup 1.0000x reference)
//
#include <hip/hip_runtime.h>
#include <stdint.h>

#define T_SEQ 256
#define B_SZ  64
#define HID   512
#define G4    2048   // 4*HID
#define E_DIM 300
#define E_PAD 320

typedef float f32x4 __attribute__((ext_vector_type(4)));
typedef short bf16x8 __attribute__((ext_vector_type(8)));
typedef short s16x4 __attribute__((ext_vector_type(4)));
typedef unsigned int u32x4 __attribute__((ext_vector_type(4)));

__device__ __forceinline__ unsigned short f2bf(float f) {
    union { float f; unsigned u; } v; v.f = f;
    unsigned r = v.u + 0x7FFF + ((v.u >> 16) & 1);   // RNE
    return (unsigned short)(r >> 16);
}
__device__ __forceinline__ float bf2f(unsigned short b) {
    union { unsigned u; float f; } v; v.u = ((unsigned)b) << 16;
    return v.f;
}
// fast sigmoid/tanh via native exp (v_exp_f32)
__device__ __forceinline__ float sigm_f(float x) { return 1.0f / (1.0f + __expf(-x)); }
__device__ __forceinline__ float tanh_f(float x) {
    float e = __expf(-2.0f * fabsf(x));
    float t = (1.0f - e) / (1.0f + e);
    return x < 0.0f ? -t : t;
}

// ---------------- diagnostic sentinel (ws too small) ----------------
__global__ void k_sentinel(float* out) { out[0] = 12345.0f; }

// ---------------- embedding gather + cast/pad to bf16 (t-major rows) ----------------
__global__ __launch_bounds__(256) void k_gather(const int* __restrict__ ids,
                                                const float* __restrict__ emb,
                                                unsigned short* __restrict__ x) {
    int w = threadIdx.x >> 6, lane = threadIdx.x & 63;
    int m = blockIdx.x * 4 + w;                  // row m = t*64 + b
    int b = m & 63, t = m >> 6;
    int id = ids[b * T_SEQ + t];
    const float* e = emb + (size_t)id * E_DIM;
    unsigned short* xr = x + (size_t)m * E_PAD;
    for (int k = lane; k < E_PAD; k += 64)
        xr[k] = (k < E_DIM) ? f2bf(e[k]) : (unsigned short)0;
}

// ---------------- fused fp32 -> bf16 casts (8 jobs, one launch) ----------------
struct CastJobs {
    const float* s[8];
    unsigned short* d[8];
    int ks[8];
    int kp[8];
};
__global__ __launch_bounds__(256) void k_castall(CastJobs jobs) {
    int job = blockIdx.x >> 11;                  // 8 jobs x 2048 rows
    int row = blockIdx.x & 2047;
    int Ks = jobs.ks[job], Kp = jobs.kp[job];
    const float* s = jobs.s[job] + (size_t)row * Ks;
    unsigned short* d = jobs.d[job] + (size_t)row * Kp;
    for (int k = threadIdx.x; k < Kp; k += 256)
        d[k] = (k < Ks) ? f2bf(s[k]) : (unsigned short)0;
}

// ---------------- bf16 GEMM (128x128 tile) -> pre2[t][fi][q][jg][j][g][rr] ----------------
__global__ __launch_bounds__(256) void k_gemm(const unsigned short* __restrict__ A,
                                              const unsigned short* __restrict__ W,
                                              const float* __restrict__ bih,
                                              const float* __restrict__ bhh,
                                              unsigned short* __restrict__ outp,
                                              int Ka) {
    __shared__ __align__(16) short As[128][40];
    __shared__ __align__(16) short Bs[128][40];
    int tid = threadIdx.x;
    int w = tid >> 6, lane = tid & 63;
    int wr = w >> 1, wc = w & 1;
    int q = lane >> 4, j = lane & 15;
    int m0 = blockIdx.x * 128, n0 = blockIdx.y * 128;

    f32x4 acc[4][4];
    #pragma unroll
    for (int fi = 0; fi < 4; ++fi)
        #pragma unroll
        for (int nt = 0; nt < 4; ++nt) { acc[fi][nt][0]=0.f; acc[fi][nt][1]=0.f; acc[fi][nt][2]=0.f; acc[fi][nt][3]=0.f; }

    for (int k0 = 0; k0 < Ka; k0 += 32) {
        #pragma unroll
        for (int c = 0; c < 2; ++c) {
            int ch = tid + c * 256;
            int row = ch >> 2, cho = ch & 3;
            *(bf16x8*)&As[row][cho * 8] = *(const bf16x8*)&A[(size_t)(m0 + row) * Ka + k0 + cho * 8];
            *(bf16x8*)&Bs[row][cho * 8] = *(const bf16x8*)&W[(size_t)(n0 + row) * Ka + k0 + cho * 8];
        }
        __syncthreads();
        bf16x8 af[4], bf[4];
        #pragma unroll
        for (int fi = 0; fi < 4; ++fi)
            af[fi] = *(const bf16x8*)&As[wr * 64 + fi * 16 + j][q * 8];
        #pragma unroll
        for (int nt = 0; nt < 4; ++nt)
            bf[nt] = *(const bf16x8*)&Bs[wc * 64 + nt * 16 + j][q * 8];
        #pragma unroll
        for (int fi = 0; fi < 4; ++fi)
            #pragma unroll
            for (int nt = 0; nt < 4; ++nt)
                acc[fi][nt] = __builtin_amdgcn_mfma_f32_16x16x32_bf16(af[fi], bf[nt], acc[fi][nt], 0, 0, 0);
        __syncthreads();
    }
    int t = blockIdx.x * 2 + wr;
    #pragma unroll
    for (int fi = 0; fi < 4; ++fi) {
        #pragma unroll
        for (int nt = 0; nt < 4; ++nt) {
            int col = n0 + wc * 64 + nt * 16 + j;
            int g = col >> 9, jc = col & 511;
            float b0 = bih[col] + bhh[col];
            s16x4 pk;
            #pragma unroll
            for (int rr = 0; rr < 4; ++rr)
                pk[rr] = (short)f2bf(acc[fi][nt][rr] + b0);
            size_t idx = (((((size_t)t * 4 + fi) * 4 + q) * 32 + (jc >> 4)) * 16 + (jc & 15)) * 16 + g * 4;
            *(s16x4*)&outp[idx] = pk;             // one 8B store
        }
    }
}

// ---------------- persistent bidirectional LSTM layer (1-wave blocks, 256 CUs) ----------------
// grid (32 jg, 4 rg, 2 dir) = 256 blocks x 64 thr: identical per-wave work to
// r13's 4-wave blocks (4 gate-chains x 16 MFMA, lane-local gate combine) but
// the W_hh re-stream (64KB/wave/step from L2; VGPR cap forces it) is spread
// over 256 CUs instead of 64 -> 4x less per-CU L2 serialization. h exchange
// via sc0/sc1 LLC ops; barrier = relaxed flag store + 32-flag poll (proven
// r13 semantics; release would emit buffer_wbl2 per step — r10->r11).
__global__ __launch_bounds__(64, 1) void k_lstm_layer(
        const unsigned short* __restrict__ pre2_f, const unsigned short* __restrict__ pre2_b,
        const unsigned short* __restrict__ whh_f, const unsigned short* __restrict__ whh_b,
        unsigned short* __restrict__ h_pp,        // bf16 [2 parity][2 dir][64][512]
        int* __restrict__ flags,                  // [2][4][32] flags, 64B-padded
        unsigned short* __restrict__ x1,          // mode 0 out: [t][b][1024]
        unsigned short* __restrict__ h1f, unsigned short* __restrict__ h1b, // mode 1: [t][b][512]
        int mode, int flag_base) {
    int tid = threadIdx.x;
    int jg = blockIdx.x, rg = blockIdx.y, dir = blockIdx.z;
    int r0 = rg * 16, q = tid >> 4, j = tid & 15;
    const unsigned short* pre2 = dir ? pre2_b : pre2_f;
    const unsigned short* whh = dir ? whh_b : whh_f;
    int* gbase = flags + ((dir * 4 + rg) * 32) * 16;  // group's 32 flags (64B apart)

    __shared__ __align__(16) short ws_a[16 * 512];    // 16 KiB h tile (swizzled)

    // ---- W_hh fragments (compiler decides residency; reloads hit L2) ----
    bf16x8 breg[4][16];
    #pragma unroll
    for (int g = 0; g < 4; ++g)
        #pragma unroll
        for (int kc = 0; kc < 16; ++kc)
            breg[g][kc] = *(const bf16x8*)(whh + (size_t)(g * 512 + jg * 16 + j) * 512 + q * 8 + kc * 32);

    float cr[4];
    #pragma unroll
    for (int rr = 0; rr < 4; ++rr) cr[rr] = 0.f;

    // A-frag LDS addressing
    int aswz = (j & 7) << 4;
    const char* abase = (const char*)ws_a + (j << 10);
    int ko16 = q << 4;

    // step-0 preactivations
    bf16x8 pcur0, pcur1;
    {
        int t0 = dir ? (T_SEQ - 1) : 0;
        const unsigned short* pp =
            pre2 + ((((((size_t)t0 * 4 + rg) * 4 + q) * 32 + jg) * 16 + j) * 16);
        pcur0 = *(const bf16x8*)pp;
        pcur1 = *(const bf16x8*)(pp + 8);
    }

    for (int s = 0; s < T_SEQ; ++s) {
        int t = dir ? (T_SEQ - 1 - s) : s;
        const unsigned short* hprev = h_pp + ((size_t)(s & 1) * 2 + dir) * (B_SZ * HID);
        unsigned short* hnext = h_pp + ((size_t)((s + 1) & 1) * 2 + dir) * (B_SZ * HID);

        f32x4 a0, a1, a2, a3;
        a0[0]=0.f;a0[1]=0.f;a0[2]=0.f;a0[3]=0.f; a1=a0; a2=a0; a3=a0;
        if (s > 0) {
            // ---- stage h tile (16 rows x 512 = 1024 x 16B) into LDS, 16 chunks/lane
            const unsigned short* hp = hprev + (size_t)r0 * HID;
            u32x4 va[16];
            #pragma unroll
            for (int c = 0; c < 16; ++c) {
                int ch = tid + c * 64;
                const void* src = hp + ((ch >> 6) << 9) + ((ch & 63) << 3);
                asm volatile("global_load_dwordx4 %0, %1, off sc0 sc1"
                             : "=v"(va[c]) : "v"(src));
            }
            asm volatile("s_waitcnt vmcnt(0)" ::: "memory");
            #pragma unroll
            for (int c = 0; c < 16; ++c) {
                int ch = tid + c * 64;
                int r = ch >> 6, o = ch & 63;
                *(u32x4*)((char*)ws_a + (r << 10) + ((o << 4) ^ ((r & 7) << 4))) = va[c];
            }
            __syncthreads();

            #pragma unroll
            for (int kc = 0; kc < 16; ++kc) {
                bf16x8 a = *(const bf16x8*)(abase + (((kc << 6) + ko16) ^ aswz));
                a0 = __builtin_amdgcn_mfma_f32_16x16x32_bf16(a, breg[0][kc], a0, 0, 0, 0);
                a1 = __builtin_amdgcn_mfma_f32_16x16x32_bf16(a, breg[1][kc], a1, 0, 0, 0);
                a2 = __builtin_amdgcn_mfma_f32_16x16x32_bf16(a, breg[2][kc], a2, 0, 0, 0);
                a3 = __builtin_amdgcn_mfma_f32_16x16x32_bf16(a, breg[3][kc], a3, 0, 0, 0);
            }
        }

        // gates: lane (q,j) holds rows q*4+rr, col jg*16+j for all 4 gates
        unsigned hbits[4];
        #pragma unroll
        for (int rr = 0; rr < 4; ++rr) {
            float iv = a0[rr] + bf2f((unsigned short)pcur0[rr]);
            float fv = a1[rr] + bf2f((unsigned short)pcur0[4 + rr]);
            float gv = a2[rr] + bf2f((unsigned short)pcur1[rr]);
            float ov = a3[rr] + bf2f((unsigned short)pcur1[4 + rr]);
            cr[rr] = sigm_f(fv) * cr[rr] + sigm_f(iv) * tanh_f(gv);
            float hh = sigm_f(ov) * tanh_f(cr[rr]);
            hbits[rr] = (unsigned)f2bf(hh);
        }

        // h sc-stores ONLY (these are what the barrier must order)
        #pragma unroll
        for (int rr = 0; rr < 4; ++rr) {
            unsigned nb = (unsigned)__shfl_xor((int)hbits[rr], 1);
            if ((j & 1) == 0) {
                unsigned pair = (hbits[rr] & 0xFFFFu) | (nb << 16);
                void* dsth = (void*)(hnext + (size_t)(r0 + q * 4 + rr) * HID + jg * 16 + j);
                asm volatile("global_store_dword %0, %1, off sc0 sc1"
                             :: "v"(dsth), "v"(pair) : "memory");
            }
        }

        // drain h stores and announce (RELAXED flag; data already at LLC)
        asm volatile("s_waitcnt vmcnt(0)" ::: "memory");
        __syncthreads();
        int target = flag_base + s + 1;
        if (tid == 0)
            __hip_atomic_store(&gbase[jg * 16], target, __ATOMIC_RELAXED, __HIP_MEMORY_SCOPE_AGENT);

        // layer outputs + next-step prefetch fly under the poll
        #pragma unroll
        for (int rr = 0; rr < 4; ++rr) {
            unsigned short hb = (unsigned short)hbits[rr];
            int brow = r0 + q * 4 + rr;
            if (mode == 0)
                x1[((size_t)t * B_SZ + brow) * 1024 + dir * HID + jg * 16 + j] = hb;   // t-major
            else {
                unsigned short* o = dir ? h1b : h1f;
                o[((size_t)t * B_SZ + brow) * HID + jg * 16 + j] = hb;
            }
        }
        bf16x8 pn0, pn1;
        {
            int sn = (s + 1 < T_SEQ) ? s + 1 : s;
            int tn = dir ? (T_SEQ - 1 - sn) : sn;
            const unsigned short* pp =
                pre2 + ((((((size_t)tn * 4 + rg) * 4 + q) * 32 + jg) * 16 + j) * 16);
            pn0 = *(const bf16x8*)pp;
            pn1 = *(const bf16x8*)(pp + 8);
        }

        if (tid < 32) {
            while (__hip_atomic_load(&gbase[tid * 16], __ATOMIC_RELAXED, __HIP_MEMORY_SCOPE_AGENT) < target) {}
        }
        __syncthreads();
        pcur0 = pn0; pcur1 = pn1;
    }
}

// ---------------- scores + per-token masked squared error ----------------
__global__ __launch_bounds__(256) void k_score(const unsigned short* __restrict__ h1f,
                                               const unsigned short* __restrict__ h1b,
                                               const float* __restrict__ lin_w,
                                               const float* __restrict__ lin_b,
                                               const float* __restrict__ labels,
                                               const float* __restrict__ masks,
                                               float* __restrict__ err) {
    int w = threadIdx.x >> 6, lane = threadIdx.x & 63;
    int idx = blockIdx.x * 4 + w;                // 0..16383
    int b = idx >> 8, t = idx & 255;
    size_t base = ((size_t)t * B_SZ + b) * HID + lane * 8;
    bf16x8 hf = *(const bf16x8*)(h1f + base);
    bf16x8 hb = *(const bf16x8*)(h1b + base);
    float sum = 0.f;
    #pragma unroll
    for (int i = 0; i < 8; ++i) {
        float m = 0.5f * (bf2f((unsigned short)hf[i]) + bf2f((unsigned short)hb[i]));
        sum += m * lin_w[lane * 8 + i];
    }
    #pragma unroll
    for (int off = 32; off; off >>= 1) sum += __shfl_xor(sum, off);
    if (lane == 0) {
        float sc = 1.0f / (1.0f + expf(-(sum + lin_b[0])));
        float d = sc - labels[b * 256 + t];
        err[b * 256 + t] = d * d * masks[b * 256 + t];
    }
}

// ---------------- final reduction to scalar loss ----------------
__global__ void k_loss(const float* __restrict__ err, const float* __restrict__ masks,
                       float* __restrict__ out) {
    int lane = threadIdx.x;                      // 64 threads, 1 wave
    float se = 0.f, sm = 0.f;
    for (int t = 0; t < 256; ++t) {
        se += err[lane * 256 + t];
        sm += masks[lane * 256 + t];
    }
    float v = se / sm;
    #pragma unroll
    for (int off = 32; off; off >>= 1) v += __shfl_xor(v, off);
    if (lane == 0) out[0] = v * (1.0f / 64.0f);
}

extern "C" void kernel_launch(void* const* d_in, const int* in_sizes, int n_in,
                              void* d_out, int out_size, void* d_ws, size_t ws_size,
                              hipStream_t stream) {
    const int*   ids    = (const int*)d_in[0];
    const float* masks  = (const float*)d_in[1];
    const float* labels = (const float*)d_in[2];
    const float* emb    = (const float*)d_in[3];
    const float* lin_w  = (const float*)d_in[4];
    const float* lin_b  = (const float*)d_in[5];
    // order: 0=l0f, 1=l0b, 2=l1f, 3=l1b
    const float* w_ih[4] = {(const float*)d_in[6],  (const float*)d_in[10],
                            (const float*)d_in[14], (const float*)d_in[18]};
    const float* w_hh[4] = {(const float*)d_in[7],  (const float*)d_in[11],
                            (const float*)d_in[15], (const float*)d_in[19]};
    const float* b_ih[4] = {(const float*)d_in[8],  (const float*)d_in[12],
                            (const float*)d_in[16], (const float*)d_in[20]};
    const float* b_hh[4] = {(const float*)d_in[9],  (const float*)d_in[13],
                            (const float*)d_in[17], (const float*)d_in[21]};

    // ---- workspace layout with lifetime aliasing (~185 MiB) ----
    const size_t PRE_B   = (size_t)T_SEQ * B_SZ * G4 * 2;     // 67,108,864
    const size_t SH_B    = (size_t)16384 * 1024 * 2;          // 33,554,432 shared region
    const size_t WHH_B   = (size_t)G4 * HID * 2;              // 2,097,152
    const size_t WT1_B   = (size_t)G4 * 1024 * 2;             // 4,194,304
    const size_t HPP_B   = (size_t)2 * 2 * B_SZ * HID * 2;    // 262,144
    const size_t FLG_B   = (size_t)2 * 4 * 32 * 64;           // 16,384 (32 flags/group, 64B pad)
    const size_t ERR_B   = (size_t)B_SZ * T_SEQ * 4;          // 65,536
    const size_t REQUIRED = 2 * PRE_B + SH_B + 4 * WHH_B + 2 * WT1_B + HPP_B + FLG_B + ERR_B;
    if (REQUIRED > ws_size) {
        k_sentinel<<<1, 1, 0, stream>>>((float*)d_out);
        return;
    }

    char* base = (char*)d_ws;
    unsigned short* pre_f = (unsigned short*)(base);
    unsigned short* pre_b = (unsigned short*)(base + PRE_B);
    char* sh = base + 2 * PRE_B;
    unsigned short* x_bf = (unsigned short*)(sh);                                        // phase A-B
    unsigned short* wt0f = (unsigned short*)(sh + (size_t)16384 * E_PAD * 2);
    unsigned short* wt0b = (unsigned short*)(sh + (size_t)16384 * E_PAD * 2 + (size_t)2048 * E_PAD * 2);
    unsigned short* x1   = (unsigned short*)(sh);                                        // phase C-D
    unsigned short* h1f  = (unsigned short*)(sh);                                        // phase E-F
    unsigned short* h1b  = (unsigned short*)(sh + (size_t)T_SEQ * B_SZ * HID * 2);
    char* q = sh + SH_B;
    unsigned short* whhb[4];
    for (int i = 0; i < 4; ++i) { whhb[i] = (unsigned short*)q; q += WHH_B; }
    unsigned short* wt1f = (unsigned short*)q; q += WT1_B;
    unsigned short* wt1b = (unsigned short*)q; q += WT1_B;
    unsigned short* h_pp = (unsigned short*)q; q += HPP_B;
    int* flags = (int*)q; q += FLG_B;
    float* err = (float*)q; q += ERR_B;

    hipMemsetAsync(flags, 0, FLG_B, stream);

    // 1. gather + fused casts
    k_gather<<<4096, 256, 0, stream>>>(ids, emb, x_bf);
    CastJobs cj;
    cj.s[0] = w_ih[0]; cj.d[0] = wt0f; cj.ks[0] = E_DIM; cj.kp[0] = E_PAD;
    cj.s[1] = w_ih[1]; cj.d[1] = wt0b; cj.ks[1] = E_DIM; cj.kp[1] = E_PAD;
    cj.s[2] = w_ih[2]; cj.d[2] = wt1f; cj.ks[2] = 1024;  cj.kp[2] = 1024;
    cj.s[3] = w_ih[3]; cj.d[3] = wt1b; cj.ks[3] = 1024;  cj.kp[3] = 1024;
    for (int i = 0; i < 4; ++i) {
        cj.s[4 + i] = w_hh[i]; cj.d[4 + i] = whhb[i]; cj.ks[4 + i] = 512; cj.kp[4 + i] = 512;
    }
    k_castall<<<16384, 256, 0, stream>>>(cj);

    dim3 gemm_grid(16384 / 128, 2048 / 128);     // 128x128 tiles
    // 2. layer-0 input projections (t-major rows, write pre2 layout)
    k_gemm<<<gemm_grid, 256, 0, stream>>>(x_bf, wt0f, b_ih[0], b_hh[0], pre_f, E_PAD);
    k_gemm<<<gemm_grid, 256, 0, stream>>>(x_bf, wt0b, b_ih[1], b_hh[1], pre_b, E_PAD);

    // 3. layer-0 recurrence (persistent, 256 1-wave blocks; writes x1 t-major)
    dim3 rec_grid(32, 4, 2);
    k_lstm_layer<<<rec_grid, 64, 0, stream>>>(pre_f, pre_b, whhb[0], whhb[1],
                                              h_pp, flags, x1, nullptr, nullptr, 0, 0);

    // 4. layer-1 input projections (pre buffers reused)
    k_gemm<<<gemm_grid, 256, 0, stream>>>(x1, wt1f, b_ih[2], b_hh[2], pre_f, 1024);
    k_gemm<<<gemm_grid, 256, 0, stream>>>(x1, wt1b, b_ih[3], b_hh[3], pre_b, 1024);

    // 5. layer-1 recurrence (persistent; flag targets continue 257..512)
    k_lstm_layer<<<rec_grid, 64, 0, stream>>>(pre_f, pre_b, whhb[2], whhb[3],
                                              h_pp, flags, nullptr, h1f, h1b, 1, 256);

    // 6. scores + loss
    k_score<<<4096, 256, 0, stream>>>(h1f, h1b, lin_w, lin_b, labels, masks, err);
    k_loss<<<1, 64, 0, stream>>>(err, masks, (float*)d_out);
}

// Round 18
// 2272.464 us; speedup vs baseline: 1.0581x; 1.0581x over previous
//
#include <hip/hip_runtime.h>
#include <stdint.h>

#define T_SEQ 256
#define B_SZ  64
#define HID   512
#define G4    2048   // 4*HID
#define E_DIM 300
#define E_PAD 320

typedef float f32x4 __attribute__((ext_vector_type(4)));
typedef short bf16x8 __attribute__((ext_vector_type(8)));
typedef short s16x4 __attribute__((ext_vector_type(4)));
typedef unsigned int u32x4 __attribute__((ext_vector_type(4)));

__device__ __forceinline__ unsigned short f2bf(float f) {
    union { float f; unsigned u; } v; v.f = f;
    unsigned r = v.u + 0x7FFF + ((v.u >> 16) & 1);   // RNE
    return (unsigned short)(r >> 16);
}
__device__ __forceinline__ float bf2f(unsigned short b) {
    union { unsigned u; float f; } v; v.u = ((unsigned)b) << 16;
    return v.f;
}
// fast sigmoid/tanh via native exp (v_exp_f32)
__device__ __forceinline__ float sigm_f(float x) { return 1.0f / (1.0f + __expf(-x)); }
__device__ __forceinline__ float tanh_f(float x) {
    float e = __expf(-2.0f * fabsf(x));
    float t = (1.0f - e) / (1.0f + e);
    return x < 0.0f ? -t : t;
}

// ---------------- diagnostic sentinel (ws too small) ----------------
__global__ void k_sentinel(float* out) { out[0] = 12345.0f; }

// ---------------- embedding gather + cast/pad to bf16 (t-major rows) ----------------
__global__ __launch_bounds__(256) void k_gather(const int* __restrict__ ids,
                                                const float* __restrict__ emb,
                                                unsigned short* __restrict__ x) {
    int w = threadIdx.x >> 6, lane = threadIdx.x & 63;
    int m = blockIdx.x * 4 + w;                  // row m = t*64 + b
    int b = m & 63, t = m >> 6;
    int id = ids[b * T_SEQ + t];
    const float* e = emb + (size_t)id * E_DIM;
    unsigned short* xr = x + (size_t)m * E_PAD;
    for (int k = lane; k < E_PAD; k += 64)
        xr[k] = (k < E_DIM) ? f2bf(e[k]) : (unsigned short)0;
}

// ---------------- fused fp32 -> bf16 casts (8 jobs, one launch) ----------------
struct CastJobs {
    const float* s[8];
    unsigned short* d[8];
    int ks[8];
    int kp[8];
};
__global__ __launch_bounds__(256) void k_castall(CastJobs jobs) {
    int job = blockIdx.x >> 11;                  // 8 jobs x 2048 rows
    int row = blockIdx.x & 2047;
    int Ks = jobs.ks[job], Kp = jobs.kp[job];
    const float* s = jobs.s[job] + (size_t)row * Ks;
    unsigned short* d = jobs.d[job] + (size_t)row * Kp;
    for (int k = threadIdx.x; k < Kp; k += 256)
        d[k] = (k < Ks) ? f2bf(s[k]) : (unsigned short)0;
}

// ---------------- bf16 GEMM (128x128 tile) -> pre2[t][fi][q][jg][j][g][rr] ----------------
// A: [16384][Ka] bf16 row-major, m = t*64 + b (t-major). W: [2048][Ka].
// 4 waves in 2x2; wave (wr,wc) computes rows wr*64+fi*16.., cols wc*64+nt*16..
// Packed 8B epilogue: b = fi*16 + q*4 + rr -> rr is pre2's innermost index.
__global__ __launch_bounds__(256) void k_gemm(const unsigned short* __restrict__ A,
                                              const unsigned short* __restrict__ W,
                                              const float* __restrict__ bih,
                                              const float* __restrict__ bhh,
                                              unsigned short* __restrict__ outp,
                                              int Ka) {
    __shared__ __align__(16) short As[128][40];
    __shared__ __align__(16) short Bs[128][40];
    int tid = threadIdx.x;
    int w = tid >> 6, lane = tid & 63;
    int wr = w >> 1, wc = w & 1;
    int q = lane >> 4, j = lane & 15;
    int m0 = blockIdx.x * 128, n0 = blockIdx.y * 128;

    f32x4 acc[4][4];
    #pragma unroll
    for (int fi = 0; fi < 4; ++fi)
        #pragma unroll
        for (int nt = 0; nt < 4; ++nt) { acc[fi][nt][0]=0.f; acc[fi][nt][1]=0.f; acc[fi][nt][2]=0.f; acc[fi][nt][3]=0.f; }

    for (int k0 = 0; k0 < Ka; k0 += 32) {
        #pragma unroll
        for (int c = 0; c < 2; ++c) {
            int ch = tid + c * 256;
            int row = ch >> 2, cho = ch & 3;
            *(bf16x8*)&As[row][cho * 8] = *(const bf16x8*)&A[(size_t)(m0 + row) * Ka + k0 + cho * 8];
            *(bf16x8*)&Bs[row][cho * 8] = *(const bf16x8*)&W[(size_t)(n0 + row) * Ka + k0 + cho * 8];
        }
        __syncthreads();
        bf16x8 af[4], bf[4];
        #pragma unroll
        for (int fi = 0; fi < 4; ++fi)
            af[fi] = *(const bf16x8*)&As[wr * 64 + fi * 16 + j][q * 8];
        #pragma unroll
        for (int nt = 0; nt < 4; ++nt)
            bf[nt] = *(const bf16x8*)&Bs[wc * 64 + nt * 16 + j][q * 8];
        #pragma unroll
        for (int fi = 0; fi < 4; ++fi)
            #pragma unroll
            for (int nt = 0; nt < 4; ++nt)
                acc[fi][nt] = __builtin_amdgcn_mfma_f32_16x16x32_bf16(af[fi], bf[nt], acc[fi][nt], 0, 0, 0);
        __syncthreads();
    }
    // D layout: col = lane&15, row = (lane>>4)*4 + reg   [HW-verified]
    int t = blockIdx.x * 2 + wr;
    #pragma unroll
    for (int fi = 0; fi < 4; ++fi) {
        #pragma unroll
        for (int nt = 0; nt < 4; ++nt) {
            int col = n0 + wc * 64 + nt * 16 + j;
            int g = col >> 9, jc = col & 511;
            float b0 = bih[col] + bhh[col];
            s16x4 pk;
            #pragma unroll
            for (int rr = 0; rr < 4; ++rr)
                pk[rr] = (short)f2bf(acc[fi][nt][rr] + b0);
            size_t idx = (((((size_t)t * 4 + fi) * 4 + q) * 32 + (jc >> 4)) * 16 + (jc & 15)) * 16 + g * 4;
            *(s16x4*)&outp[idx] = pk;             // one 8B store
        }
    }
}

// ---------------- persistent bidirectional LSTM layer (r13/r16 proven config) ----------------
// grid (8 jgg, 4 rg, 2 dir) = 64 blocks x 256 thr. Wave w owns jg = jgg*4+w:
// computes all 4 gate-tiles (16 rows x 16 cols, K=512) -> gate combine is
// lane-local. A-tile staged per step into LDS (sc0/sc1 LLC-coherent loads).
// Barrier: vmcnt(0)+syncthreads drain, then RELAXED flag store + 8-flag poll
// (release would emit buffer_wbl2 = full L2 writeback per step; r10->r11).
__global__ __launch_bounds__(256, 1) void k_lstm_layer(
        const unsigned short* __restrict__ pre2_f, const unsigned short* __restrict__ pre2_b,
        const unsigned short* __restrict__ whh_f, const unsigned short* __restrict__ whh_b,
        unsigned short* __restrict__ h_pp,        // bf16 [2 parity][2 dir][64][512]
        int* __restrict__ flags,                  // [2][4][8] flags, 64B-padded
        unsigned short* __restrict__ x1,          // mode 0 out: [t][b][1024]
        unsigned short* __restrict__ h1f, unsigned short* __restrict__ h1b, // mode 1: [t][b][512]
        int mode, int flag_base) {
    int tid = threadIdx.x, w = tid >> 6, lane = tid & 63;
    int jgg = blockIdx.x, rg = blockIdx.y, dir = blockIdx.z;
    int jg = jgg * 4 + w;                        // 0..31
    int r0 = rg * 16, q = lane >> 4, j = lane & 15;
    const unsigned short* pre2 = dir ? pre2_b : pre2_f;
    const unsigned short* whh = dir ? whh_b : whh_f;
    int* gbase = flags + ((dir * 4 + rg) * 8) * 16;   // group's 8 flags (64B apart)

    __shared__ __align__(16) short ws_a[16 * 512];    // 16 KiB h tile (swizzled)

    // ---- W_hh fragments (compiler decides residency; reloads hit L2) ----
    bf16x8 breg[4][16];
    #pragma unroll
    for (int g = 0; g < 4; ++g)
        #pragma unroll
        for (int kc = 0; kc < 16; ++kc)
            breg[g][kc] = *(const bf16x8*)(whh + (size_t)(g * 512 + jg * 16 + j) * 512 + q * 8 + kc * 32);

    float cr[4];
    #pragma unroll
    for (int rr = 0; rr < 4; ++rr) cr[rr] = 0.f;

    // A-frag LDS addressing
    int aswz = (j & 7) << 4;
    const char* abase = (const char*)ws_a + (j << 10);
    int ko16 = q << 4;

    // step-0 preactivations
    bf16x8 pcur0, pcur1;
    {
        int t0 = dir ? (T_SEQ - 1) : 0;
        const unsigned short* pp =
            pre2 + ((((((size_t)t0 * 4 + rg) * 4 + q) * 32 + jg) * 16 + j) * 16);
        pcur0 = *(const bf16x8*)pp;
        pcur1 = *(const bf16x8*)(pp + 8);
    }

    for (int s = 0; s < T_SEQ; ++s) {
        int t = dir ? (T_SEQ - 1 - s) : s;
        const unsigned short* hprev = h_pp + ((size_t)(s & 1) * 2 + dir) * (B_SZ * HID);
        unsigned short* hnext = h_pp + ((size_t)((s + 1) & 1) * 2 + dir) * (B_SZ * HID);

        f32x4 a0, a1, a2, a3;
        a0[0]=0.f;a0[1]=0.f;a0[2]=0.f;a0[3]=0.f; a1=a0; a2=a0; a3=a0;
        if (s > 0) {
            // ---- stage h tile (16 rows x 512) into LDS via coherent 16B loads
            const unsigned short* hp = hprev + (size_t)r0 * HID;
            u32x4 va[4];
            #pragma unroll
            for (int c = 0; c < 4; ++c) {
                int ch = tid + c * 256;                       // 1024 chunks of 16B
                const void* src = hp + ((ch >> 6) << 9) + ((ch & 63) << 3);
                asm volatile("global_load_dwordx4 %0, %1, off sc0 sc1"
                             : "=v"(va[c]) : "v"(src));
            }
            asm volatile("s_waitcnt vmcnt(0)" ::: "memory");
            #pragma unroll
            for (int c = 0; c < 4; ++c) {
                int ch = tid + c * 256;
                int r = ch >> 6, o = ch & 63;
                *(u32x4*)((char*)ws_a + (r << 10) + ((o << 4) ^ ((r & 7) << 4))) = va[c];
            }
            __syncthreads();

            #pragma unroll
            for (int kc = 0; kc < 16; ++kc) {
                bf16x8 a = *(const bf16x8*)(abase + (((kc << 6) + ko16) ^ aswz));
                a0 = __builtin_amdgcn_mfma_f32_16x16x32_bf16(a, breg[0][kc], a0, 0, 0, 0);
                a1 = __builtin_amdgcn_mfma_f32_16x16x32_bf16(a, breg[1][kc], a1, 0, 0, 0);
                a2 = __builtin_amdgcn_mfma_f32_16x16x32_bf16(a, breg[2][kc], a2, 0, 0, 0);
                a3 = __builtin_amdgcn_mfma_f32_16x16x32_bf16(a, breg[3][kc], a3, 0, 0, 0);
            }
        }

        // gates: lane (q,j) holds rows q*4+rr, col jg*16+j for all 4 gates
        unsigned hbits[4];
        #pragma unroll
        for (int rr = 0; rr < 4; ++rr) {
            float iv = a0[rr] + bf2f((unsigned short)pcur0[rr]);
            float fv = a1[rr] + bf2f((unsigned short)pcur0[4 + rr]);
            float gv = a2[rr] + bf2f((unsigned short)pcur1[rr]);
            float ov = a3[rr] + bf2f((unsigned short)pcur1[4 + rr]);
            cr[rr] = sigm_f(fv) * cr[rr] + sigm_f(iv) * tanh_f(gv);
            float hh = sigm_f(ov) * tanh_f(cr[rr]);
            hbits[rr] = (unsigned)f2bf(hh);
        }

        // h sc-stores ONLY (these are what the barrier must order)
        #pragma unroll
        for (int rr = 0; rr < 4; ++rr) {
            unsigned nb = (unsigned)__shfl_xor((int)hbits[rr], 1);
            if ((j & 1) == 0) {
                unsigned pair = (hbits[rr] & 0xFFFFu) | (nb << 16);
                void* dsth = (void*)(hnext + (size_t)(r0 + q * 4 + rr) * HID + jg * 16 + j);
                asm volatile("global_store_dword %0, %1, off sc0 sc1"
                             :: "v"(dsth), "v"(pair) : "memory");
            }
        }

        // drain h stores and announce (RELAXED flag; data already at LLC)
        asm volatile("s_waitcnt vmcnt(0)" ::: "memory");
        __syncthreads();
        int target = flag_base + s + 1;
        if (tid == 0)
            __hip_atomic_store(&gbase[jgg * 16], target, __ATOMIC_RELAXED, __HIP_MEMORY_SCOPE_AGENT);

        // layer outputs + next-step prefetch fly under the poll
        #pragma unroll
        for (int rr = 0; rr < 4; ++rr) {
            unsigned short hb = (unsigned short)hbits[rr];
            int brow = r0 + q * 4 + rr;
            if (mode == 0)
                x1[((size_t)t * B_SZ + brow) * 1024 + dir * HID + jg * 16 + j] = hb;   // t-major
            else {
                unsigned short* o = dir ? h1b : h1f;
                o[((size_t)t * B_SZ + brow) * HID + jg * 16 + j] = hb;
            }
        }
        bf16x8 pn0, pn1;
        {
            int sn = (s + 1 < T_SEQ) ? s + 1 : s;
            int tn = dir ? (T_SEQ - 1 - sn) : sn;
            const unsigned short* pp =
                pre2 + ((((((size_t)tn * 4 + rg) * 4 + q) * 32 + jg) * 16 + j) * 16);
            pn0 = *(const bf16x8*)pp;
            pn1 = *(const bf16x8*)(pp + 8);
        }

        if (tid < 8) {
            while (__hip_atomic_load(&gbase[tid * 16], __ATOMIC_RELAXED, __HIP_MEMORY_SCOPE_AGENT) < target) {}
        }
        __syncthreads();
        pcur0 = pn0; pcur1 = pn1;
    }
}

// ---------------- scores + per-token masked squared error ----------------
__global__ __launch_bounds__(256) void k_score(const unsigned short* __restrict__ h1f,
                                               const unsigned short* __restrict__ h1b,
                                               const float* __restrict__ lin_w,
                                               const float* __restrict__ lin_b,
                                               const float* __restrict__ labels,
                                               const float* __restrict__ masks,
                                               float* __restrict__ err) {
    int w = threadIdx.x >> 6, lane = threadIdx.x & 63;
    int idx = blockIdx.x * 4 + w;                // 0..16383
    int b = idx >> 8, t = idx & 255;
    size_t base = ((size_t)t * B_SZ + b) * HID + lane * 8;
    bf16x8 hf = *(const bf16x8*)(h1f + base);
    bf16x8 hb = *(const bf16x8*)(h1b + base);
    float sum = 0.f;
    #pragma unroll
    for (int i = 0; i < 8; ++i) {
        float m = 0.5f * (bf2f((unsigned short)hf[i]) + bf2f((unsigned short)hb[i]));
        sum += m * lin_w[lane * 8 + i];
    }
    #pragma unroll
    for (int off = 32; off; off >>= 1) sum += __shfl_xor(sum, off);
    if (lane == 0) {
        float sc = 1.0f / (1.0f + expf(-(sum + lin_b[0])));
        float d = sc - labels[b * 256 + t];
        err[b * 256 + t] = d * d * masks[b * 256 + t];
    }
}

// ---------------- final reduction to scalar loss ----------------
__global__ void k_loss(const float* __restrict__ err, const float* __restrict__ masks,
                       float* __restrict__ out) {
    int lane = threadIdx.x;                      // 64 threads, 1 wave
    float se = 0.f, sm = 0.f;
    for (int t = 0; t < 256; ++t) {
        se += err[lane * 256 + t];
        sm += masks[lane * 256 + t];
    }
    float v = se / sm;
    #pragma unroll
    for (int off = 32; off; off >>= 1) v += __shfl_xor(v, off);
    if (lane == 0) out[0] = v * (1.0f / 64.0f);
}

extern "C" void kernel_launch(void* const* d_in, const int* in_sizes, int n_in,
                              void* d_out, int out_size, void* d_ws, size_t ws_size,
                              hipStream_t stream) {
    const int*   ids    = (const int*)d_in[0];
    const float* masks  = (const float*)d_in[1];
    const float* labels = (const float*)d_in[2];
    const float* emb    = (const float*)d_in[3];
    const float* lin_w  = (const float*)d_in[4];
    const float* lin_b  = (const float*)d_in[5];
    // order: 0=l0f, 1=l0b, 2=l1f, 3=l1b
    const float* w_ih[4] = {(const float*)d_in[6],  (const float*)d_in[10],
                            (const float*)d_in[14], (const float*)d_in[18]};
    const float* w_hh[4] = {(const float*)d_in[7],  (const float*)d_in[11],
                            (const float*)d_in[15], (const float*)d_in[19]};
    const float* b_ih[4] = {(const float*)d_in[8],  (const float*)d_in[12],
                            (const float*)d_in[16], (const float*)d_in[20]};
    const float* b_hh[4] = {(const float*)d_in[9],  (const float*)d_in[13],
                            (const float*)d_in[17], (const float*)d_in[21]};

    // ---- workspace layout with lifetime aliasing (~185 MiB) ----
    const size_t PRE_B   = (size_t)T_SEQ * B_SZ * G4 * 2;     // 67,108,864
    const size_t SH_B    = (size_t)16384 * 1024 * 2;          // 33,554,432 shared region
    const size_t WHH_B   = (size_t)G4 * HID * 2;              // 2,097,152
    const size_t WT1_B   = (size_t)G4 * 1024 * 2;             // 4,194,304
    const size_t HPP_B   = (size_t)2 * 2 * B_SZ * HID * 2;    // 262,144
    const size_t FLG_B   = (size_t)256 * 64;                  // 16,384
    const size_t ERR_B   = (size_t)B_SZ * T_SEQ * 4;          // 65,536
    const size_t REQUIRED = 2 * PRE_B + SH_B + 4 * WHH_B + 2 * WT1_B + HPP_B + FLG_B + ERR_B;
    if (REQUIRED > ws_size) {
        k_sentinel<<<1, 1, 0, stream>>>((float*)d_out);
        return;
    }

    char* base = (char*)d_ws;
    unsigned short* pre_f = (unsigned short*)(base);
    unsigned short* pre_b = (unsigned short*)(base + PRE_B);
    char* sh = base + 2 * PRE_B;
    unsigned short* x_bf = (unsigned short*)(sh);                                        // phase A-B
    unsigned short* wt0f = (unsigned short*)(sh + (size_t)16384 * E_PAD * 2);
    unsigned short* wt0b = (unsigned short*)(sh + (size_t)16384 * E_PAD * 2 + (size_t)2048 * E_PAD * 2);
    unsigned short* x1   = (unsigned short*)(sh);                                        // phase C-D
    unsigned short* h1f  = (unsigned short*)(sh);                                        // phase E-F
    unsigned short* h1b  = (unsigned short*)(sh + (size_t)T_SEQ * B_SZ * HID * 2);
    char* q = sh + SH_B;
    unsigned short* whhb[4];
    for (int i = 0; i < 4; ++i) { whhb[i] = (unsigned short*)q; q += WHH_B; }
    unsigned short* wt1f = (unsigned short*)q; q += WT1_B;
    unsigned short* wt1b = (unsigned short*)q; q += WT1_B;
    unsigned short* h_pp = (unsigned short*)q; q += HPP_B;
    int* flags = (int*)q; q += FLG_B;
    float* err = (float*)q; q += ERR_B;

    hipMemsetAsync(flags, 0, FLG_B, stream);

    // 1. gather + fused casts
    k_gather<<<4096, 256, 0, stream>>>(ids, emb, x_bf);
    CastJobs cj;
    cj.s[0] = w_ih[0]; cj.d[0] = wt0f; cj.ks[0] = E_DIM; cj.kp[0] = E_PAD;
    cj.s[1] = w_ih[1]; cj.d[1] = wt0b; cj.ks[1] = E_DIM; cj.kp[1] = E_PAD;
    cj.s[2] = w_ih[2]; cj.d[2] = wt1f; cj.ks[2] = 1024;  cj.kp[2] = 1024;
    cj.s[3] = w_ih[3]; cj.d[3] = wt1b; cj.ks[3] = 1024;  cj.kp[3] = 1024;
    for (int i = 0; i < 4; ++i) {
        cj.s[4 + i] = w_hh[i]; cj.d[4 + i] = whhb[i]; cj.ks[4 + i] = 512; cj.kp[4 + i] = 512;
    }
    k_castall<<<16384, 256, 0, stream>>>(cj);

    dim3 gemm_grid(16384 / 128, 2048 / 128);     // 128x128 tiles
    // 2. layer-0 input projections (t-major rows, write pre2 layout)
    k_gemm<<<gemm_grid, 256, 0, stream>>>(x_bf, wt0f, b_ih[0], b_hh[0], pre_f, E_PAD);
    k_gemm<<<gemm_grid, 256, 0, stream>>>(x_bf, wt0b, b_ih[1], b_hh[1], pre_b, E_PAD);

    // 3. layer-0 recurrence (persistent; writes x1 t-major)
    dim3 rec_grid(8, 4, 2);
    k_lstm_layer<<<rec_grid, 256, 0, stream>>>(pre_f, pre_b, whhb[0], whhb[1],
                                               h_pp, flags, x1, nullptr, nullptr, 0, 0);

    // 4. layer-1 input projections (pre buffers reused)
    k_gemm<<<gemm_grid, 256, 0, stream>>>(x1, wt1f, b_ih[2], b_hh[2], pre_f, 1024);
    k_gemm<<<gemm_grid, 256, 0, stream>>>(x1, wt1b, b_ih[3], b_hh[3], pre_b, 1024);

    // 5. layer-1 recurrence (persistent; flag targets continue 257..512)
    k_lstm_layer<<<rec_grid, 256, 0, stream>>>(pre_f, pre_b, whhb[2], whhb[3],
                                               h_pp, flags, nullptr, h1f, h1b, 1, 256);

    // 6. scores + loss
    k_score<<<4096, 256, 0, stream>>>(h1f, h1b, lin_w, lin_b, labels, masks, err);
    k_loss<<<1, 64, 0, stream>>>(err, masks, (float*)d_out);
}